// Round 5
// baseline (162.089 us; speedup 1.0000x reference)
//
#include <hip/hip_runtime.h>
#include <math.h>

// Problem constants
constexpr int kT = 512;
constexpr int kB = 8;
constexpr int kD = 512;
constexpr int kM = 128;
constexpr int kNPairs = kT * kB;        // 4096 independent (t,b) pairs
constexpr int kGP = 4;                  // pairs per block (gates kernel)
constexpr int kThreads = 256;

typedef float f32x4 __attribute__((ext_vector_type(4)));
typedef float f32x2 __attribute__((ext_vector_type(2)));

// ---------------------------------------------------------------------------
// Kernel A: gates. 1024 blocks x 256 threads (4 waves), 4 pairs/block.
// Wave w owns matrix {Wq,Wk,Wv,Wo}[w]; lane l owns columns {2l, 2l+1}.
// Each weight float2 is loaded ONCE and FMA'd against all 4 pairs
// (register-level reuse). x[p][d] is wave-uniform -> scalar s_load.
// 1024 blocks -> 4 blocks/CU = 16 waves/CU for L2-latency hiding.
// ---------------------------------------------------------------------------
__global__ __launch_bounds__(kThreads)
void mlstm_gates(const float* __restrict__ x,
                 const float* __restrict__ n_prev,
                 const float* __restrict__ Wq, const float* __restrict__ bq,
                 const float* __restrict__ Wk, const float* __restrict__ bk,
                 const float* __restrict__ Wv, const float* __restrict__ bv,
                 const float* __restrict__ wi, const float* __restrict__ bi,
                 const float* __restrict__ wf, const float* __restrict__ bf,
                 const float* __restrict__ Wo, const float* __restrict__ bo,
                 float* __restrict__ gq, float* __restrict__ gk,
                 float* __restrict__ gv, float* __restrict__ go,
                 float* __restrict__ gi, float* __restrict__ gf,
                 float* __restrict__ ginv,
                 float* __restrict__ out_n)
{
    __shared__ float sq[kGP][kM];     // q (for n-phase)
    __shared__ float sk[kGP][kM];     // k scaled by 1/sqrt(M)
    __shared__ float sif[kGP][2];     // i, f per pair

    const int tid = threadIdx.x;
    const int w   = tid >> 6;         // wave 0..3  <-> matrix q,k,v,o
    const int l   = tid & 63;         // lane
    const int pair_base = blockIdx.x * kGP;
    const float* __restrict__ xblk = x + (size_t)pair_base * kD;

    // ---------------- main matvec: 4 matrices in parallel across waves ------
    {
        const float* __restrict__ Wm = (w == 0) ? Wq : (w == 1) ? Wk : (w == 2) ? Wv : Wo;
        const float* __restrict__ bm = (w == 0) ? bq : (w == 1) ? bk : (w == 2) ? bv : bo;

        f32x2 acc[kGP];
        #pragma unroll
        for (int p = 0; p < kGP; ++p) acc[p] = (f32x2){0.f, 0.f};

        const int c = 2 * l;          // column base for this lane

        #pragma unroll 8
        for (int d = 0; d < kD; ++d) {
            const f32x2 w2 = *reinterpret_cast<const f32x2*>(Wm + d * kM + c);
            #pragma unroll
            for (int p = 0; p < kGP; ++p) {
                const float xv = xblk[p * kD + d];      // wave-uniform -> s_load
                const f32x2 xx = {xv, xv};
                acc[p] += xx * w2;                       // v_pk_fma_f32
            }
        }

        const f32x2 b2 = *reinterpret_cast<const f32x2*>(bm + c);
        const float inv_sqrt_m = 0.08838834764831845f;  // 1/sqrt(128)
        float* __restrict__ gm = (w == 0) ? gq : (w == 1) ? gk : (w == 2) ? gv : go;

        #pragma unroll
        for (int p = 0; p < kGP; ++p) {
            f32x2 v = acc[p] + b2;
            if (w == 1) { v.x *= inv_sqrt_m; v.y *= inv_sqrt_m; }
            if (w == 3) {
                v.x = 1.f / (1.f + expf(-v.x));
                v.y = 1.f / (1.f + expf(-v.y));
            }
            *reinterpret_cast<f32x2*>(gm + (size_t)(pair_base + p) * kM + c) = v;
            if (w == 0) *reinterpret_cast<f32x2*>(&sq[p][c]) = v;
            if (w == 1) *reinterpret_cast<f32x2*>(&sk[p][c]) = v;
        }
    }

    // ---------------- i/f gates: wave w handles pair w ----------------------
    {
        const int p = w;                  // pair 0..3
        float ip = 0.f, fp = 0.f;
        #pragma unroll
        for (int dd = 0; dd < kD / 64; ++dd) {
            const int d = l + 64 * dd;
            const float xv = xblk[p * kD + d];
            ip += xv * wi[d];
            fp += xv * wf[d];
        }
        #pragma unroll
        for (int msk = 32; msk >= 1; msk >>= 1) {
            ip += __shfl_xor(ip, msk, 64);
            fp += __shfl_xor(fp, msk, 64);
        }
        if (l == 0) {
            sif[p][0] = expf(ip + bi[0]);
            sif[p][1] = 1.f / (1.f + expf(-(fp + bf[0])));
        }
    }
    __syncthreads();

    // ---------------- n update + normalizer ---------------------------------
    if (tid < 32 * kGP) {
        const int p = tid >> 5;         // pair 0..3 (32 threads per pair)
        const int s = tid & 31;
        const size_t pi = (size_t)(pair_base + p);
        const float iv = sif[p][0];
        const float fv = sif[p][1];

        const float4 np4 = *reinterpret_cast<const float4*>(n_prev + pi * kM + 4 * s);
        const float4 k4  = *reinterpret_cast<const float4*>(&sk[p][4 * s]);
        const float4 q4  = *reinterpret_cast<const float4*>(&sq[p][4 * s]);

        float4 n4;
        n4.x = fv * np4.x + iv * k4.x;
        n4.y = fv * np4.y + iv * k4.y;
        n4.z = fv * np4.z + iv * k4.z;
        n4.w = fv * np4.w + iv * k4.w;
        *reinterpret_cast<float4*>(out_n + pi * kM + 4 * s) = n4;

        float nq = n4.x * q4.x + n4.y * q4.y + n4.z * q4.z + n4.w * q4.w;
        nq += __shfl_xor(nq, 16, 64);
        nq += __shfl_xor(nq, 8, 64);
        nq += __shfl_xor(nq, 4, 64);
        nq += __shfl_xor(nq, 2, 64);
        nq += __shfl_xor(nq, 1, 64);
        if (s == 0) {
            gi[pi]   = iv;
            gf[pi]   = fv;
            ginv[pi] = 1.f / fmaxf(fabsf(nq), 1.0f);
        }
    }
}

// ---------------------------------------------------------------------------
// Kernel B: C stream. One block per (t,b) pair -> 4096 blocks, 8 resident
// blocks/CU (32 waves = full occupancy). Read C_prev once (plain load so
// L3 retains it across replays), write C once (non-temporal), fuse
// h = C_new . q, then the tiny ht epilogue.
// ---------------------------------------------------------------------------
__global__ __launch_bounds__(kThreads)
void mlstm_stream(const float* __restrict__ C_prev,
                  const float* __restrict__ gq, const float* __restrict__ gk,
                  const float* __restrict__ gv, const float* __restrict__ go,
                  const float* __restrict__ gi, const float* __restrict__ gf,
                  const float* __restrict__ ginv,
                  float* __restrict__ out_C,
                  float* __restrict__ out_ht)
{
    const int pair = blockIdx.x;
    const int tid  = threadIdx.x;
    const int r0   = tid >> 5;      // 0..7
    const int s    = tid & 31;      // col group (cols 4s..4s+3)

    __shared__ float sv_s[kM];
    __shared__ float sh_s[kM];

    if (tid < 32)
        reinterpret_cast<float4*>(sv_s)[tid] =
            reinterpret_cast<const float4*>(gv + (size_t)pair * kM)[tid];

    const float iv = gi[pair];
    const float fv = gf[pair];
    const float4 k4 = *reinterpret_cast<const float4*>(gk + (size_t)pair * kM + 4 * s);
    const float4 q4 = *reinterpret_cast<const float4*>(gq + (size_t)pair * kM + 4 * s);
    __syncthreads();

    const size_t cbase = (size_t)pair * (kM * kM);
    const f32x4* cp = reinterpret_cast<const f32x4*>(C_prev + cbase);
    f32x4*       cn = reinterpret_cast<f32x4*>(out_C + cbase);

    float hpart[16];
    #pragma unroll
    for (int j = 0; j < 16; ++j) {
        const int fi = tid + kThreads * j;   // float4 flat index
        const int r  = r0 + 8 * j;           // row of this float4
        const float ivr = iv * sv_s[r];
        const f32x4 c4 = cp[fi];             // plain load: let L2/L3 cache
        f32x4 c_new;
        c_new.x = fv * c4.x + ivr * k4.x;
        c_new.y = fv * c4.y + ivr * k4.y;
        c_new.z = fv * c4.z + ivr * k4.z;
        c_new.w = fv * c4.w + ivr * k4.w;
        __builtin_nontemporal_store(c_new, &cn[fi]);
        hpart[j] = c_new.x * q4.x + c_new.y * q4.y
                 + c_new.z * q4.z + c_new.w * q4.w;
    }

    #pragma unroll
    for (int j = 0; j < 16; ++j) {
        float v = hpart[j];
        v += __shfl_xor(v, 16, 64);
        v += __shfl_xor(v, 8, 64);
        v += __shfl_xor(v, 4, 64);
        v += __shfl_xor(v, 2, 64);
        v += __shfl_xor(v, 1, 64);
        if (s == 0) sh_s[r0 + 8 * j] = v;
    }
    __syncthreads();

    if (tid < 32) {
        const float inv = ginv[pair];
        const float4 h4 = reinterpret_cast<const float4*>(sh_s)[tid];
        const float4 o4 = reinterpret_cast<const float4*>(go + (size_t)pair * kM)[tid];
        float4 ht4;
        ht4.x = o4.x * h4.x * inv;
        ht4.y = o4.y * h4.y * inv;
        ht4.z = o4.z * h4.z * inv;
        ht4.w = o4.w * h4.w * inv;
        reinterpret_cast<float4*>(out_ht + (size_t)pair * kM)[tid] = ht4;
    }
}

extern "C" void kernel_launch(void* const* d_in, const int* in_sizes, int n_in,
                              void* d_out, int out_size, void* d_ws, size_t ws_size,
                              hipStream_t stream) {
    const float* x      = (const float*)d_in[0];
    const float* C_prev = (const float*)d_in[1];
    const float* n_prev = (const float*)d_in[2];
    const float* Wq = (const float*)d_in[3];
    const float* bq = (const float*)d_in[4];
    const float* Wk = (const float*)d_in[5];
    const float* bk = (const float*)d_in[6];
    const float* Wv = (const float*)d_in[7];
    const float* bv = (const float*)d_in[8];
    const float* wi = (const float*)d_in[9];
    const float* bi = (const float*)d_in[10];
    const float* wf = (const float*)d_in[11];
    const float* bf = (const float*)d_in[12];
    const float* Wo = (const float*)d_in[13];
    const float* bo = (const float*)d_in[14];

    float* out    = (float*)d_out;
    float* out_ht = out;                                    // (T,B,M)
    float* out_C  = out + (size_t)kNPairs * kM;             // (T,B,M,M)
    float* out_n  = out_C + (size_t)kNPairs * kM * kM;      // (T,B,M)

    // workspace layout (floats)
    float* ws = (float*)d_ws;
    const size_t gsz = (size_t)kNPairs * kM;                // 524288
    float* gq   = ws;
    float* gk   = gq + gsz;
    float* gv   = gk + gsz;
    float* go   = gv + gsz;
    float* gi   = go + gsz;
    float* gf   = gi + kNPairs;
    float* ginv = gf + kNPairs;

    mlstm_gates<<<dim3(kNPairs / kGP), dim3(kThreads), 0, stream>>>(
        x, n_prev, Wq, bq, Wk, bk, Wv, bv, wi, bi, wf, bf, Wo, bo,
        gq, gk, gv, go, gi, gf, ginv, out_n);

    mlstm_stream<<<dim3(kNPairs), dim3(kThreads), 0, stream>>>(
        C_prev, gq, gk, gv, go, gi, gf, ginv, out_C, out_ht);
}

// Round 6
// 144.544 us; speedup vs baseline: 1.1214x; 1.1214x over previous
//
#include <hip/hip_runtime.h>
#include <math.h>

// Problem constants
constexpr int kT = 512;
constexpr int kB = 8;
constexpr int kD = 512;
constexpr int kM = 128;
constexpr int kNPairs = kT * kB;        // 4096 independent (t,b) pairs
constexpr int kGP = 8;                  // pairs per block (gates kernel)
constexpr int kThreads = 256;
constexpr int kRB = 64;                 // rows per stream block (2 blocks/pair)

typedef float f32x4 __attribute__((ext_vector_type(4)));
typedef float f32x2 __attribute__((ext_vector_type(2)));

// ---------------------------------------------------------------------------
// Kernel A: gates. 512 blocks x 256 threads (4 waves), 8 pairs/block.
// Wave w owns matrix {Wq,Wk,Wv,Wo}[w]; lane l owns columns {2l, 2l+1}.
// Each weight float2 is loaded ONCE and FMA'd against all 8 pairs
// (register-level reuse). x[p][d] is wave-uniform -> scalar s_load.
// 512 blocks keeps total weight L2 traffic at 512 MB (~15 us L2 floor).
// ---------------------------------------------------------------------------
__global__ __launch_bounds__(kThreads)
void mlstm_gates(const float* __restrict__ x,
                 const float* __restrict__ n_prev,
                 const float* __restrict__ Wq, const float* __restrict__ bq,
                 const float* __restrict__ Wk, const float* __restrict__ bk,
                 const float* __restrict__ Wv, const float* __restrict__ bv,
                 const float* __restrict__ wi, const float* __restrict__ bi,
                 const float* __restrict__ wf, const float* __restrict__ bf,
                 const float* __restrict__ Wo, const float* __restrict__ bo,
                 float* __restrict__ gq, float* __restrict__ gk,
                 float* __restrict__ gv, float* __restrict__ go,
                 float* __restrict__ gi, float* __restrict__ gf,
                 float* __restrict__ ginv,
                 float* __restrict__ out_n)
{
    __shared__ float sq[kGP][kM];     // q (for n-phase)
    __shared__ float sk[kGP][kM];     // k scaled by 1/sqrt(M)
    __shared__ float sif[kGP][2];     // i, f per pair

    const int tid = threadIdx.x;
    const int w   = tid >> 6;         // wave 0..3  <-> matrix q,k,v,o
    const int l   = tid & 63;         // lane
    const int pair_base = blockIdx.x * kGP;
    const float* __restrict__ xblk = x + (size_t)pair_base * kD;

    // ---------------- main matvec: 4 matrices in parallel across waves ------
    {
        const float* __restrict__ Wm = (w == 0) ? Wq : (w == 1) ? Wk : (w == 2) ? Wv : Wo;
        const float* __restrict__ bm = (w == 0) ? bq : (w == 1) ? bk : (w == 2) ? bv : bo;

        f32x2 acc[kGP];
        #pragma unroll
        for (int p = 0; p < kGP; ++p) acc[p] = (f32x2){0.f, 0.f};

        const int c = 2 * l;          // column base for this lane

        #pragma unroll 4
        for (int d = 0; d < kD; ++d) {
            const f32x2 w2 = *reinterpret_cast<const f32x2*>(Wm + d * kM + c);
            #pragma unroll
            for (int p = 0; p < kGP; ++p) {
                const float xv = xblk[p * kD + d];      // wave-uniform -> s_load
                const f32x2 xx = {xv, xv};
                acc[p] += xx * w2;                       // v_pk_fma_f32
            }
        }

        const f32x2 b2 = *reinterpret_cast<const f32x2*>(bm + c);
        const float inv_sqrt_m = 0.08838834764831845f;  // 1/sqrt(128)
        float* __restrict__ gm = (w == 0) ? gq : (w == 1) ? gk : (w == 2) ? gv : go;

        #pragma unroll
        for (int p = 0; p < kGP; ++p) {
            f32x2 v = acc[p] + b2;
            if (w == 1) { v.x *= inv_sqrt_m; v.y *= inv_sqrt_m; }
            if (w == 3) {
                v.x = 1.f / (1.f + expf(-v.x));
                v.y = 1.f / (1.f + expf(-v.y));
            }
            *reinterpret_cast<f32x2*>(gm + (size_t)(pair_base + p) * kM + c) = v;
            if (w == 0) *reinterpret_cast<f32x2*>(&sq[p][c]) = v;
            if (w == 1) *reinterpret_cast<f32x2*>(&sk[p][c]) = v;
        }
    }

    // ---------------- i/f gates: each half-wave handles one pair ------------
    {
        const int p = 2 * w + (l >> 5);   // pair 0..7
        const int s = l & 31;
        float ip = 0.f, fp = 0.f;
        #pragma unroll
        for (int dd = 0; dd < kD / 32; ++dd) {
            const int d = s + 32 * dd;
            const float xv = xblk[p * kD + d];
            ip += xv * wi[d];
            fp += xv * wf[d];
        }
        #pragma unroll
        for (int msk = 16; msk >= 1; msk >>= 1) {
            ip += __shfl_xor(ip, msk, 64);
            fp += __shfl_xor(fp, msk, 64);
        }
        if (s == 0) {
            sif[p][0] = expf(ip + bi[0]);
            sif[p][1] = 1.f / (1.f + expf(-(fp + bf[0])));
        }
    }
    __syncthreads();

    // ---------------- n update + normalizer ---------------------------------
    {
        const int p = tid >> 5;         // pair 0..7 (32 threads per pair)
        const int s = tid & 31;
        const size_t pi = (size_t)(pair_base + p);
        const float iv = sif[p][0];
        const float fv = sif[p][1];

        const float4 np4 = *reinterpret_cast<const float4*>(n_prev + pi * kM + 4 * s);
        const float4 k4  = *reinterpret_cast<const float4*>(&sk[p][4 * s]);
        const float4 q4  = *reinterpret_cast<const float4*>(&sq[p][4 * s]);

        float4 n4;
        n4.x = fv * np4.x + iv * k4.x;
        n4.y = fv * np4.y + iv * k4.y;
        n4.z = fv * np4.z + iv * k4.z;
        n4.w = fv * np4.w + iv * k4.w;
        *reinterpret_cast<float4*>(out_n + pi * kM + 4 * s) = n4;

        float nq = n4.x * q4.x + n4.y * q4.y + n4.z * q4.z + n4.w * q4.w;
        nq += __shfl_xor(nq, 16, 64);
        nq += __shfl_xor(nq, 8, 64);
        nq += __shfl_xor(nq, 4, 64);
        nq += __shfl_xor(nq, 2, 64);
        nq += __shfl_xor(nq, 1, 64);
        if (s == 0) {
            gi[pi]   = iv;
            gf[pi]   = fv;
            ginv[pi] = 1.f / fmaxf(fabsf(nq), 1.0f);
        }
    }
}

// ---------------------------------------------------------------------------
// Kernel B: C stream. One block per 64-row half of a pair -> 8192 blocks.
// The C.q dot is along columns, so a row-split keeps the h reduction fully
// block-local. 8 float4/thread with an explicit load batch (8 loads in
// flight in 32 VGPRs). Plain loads (L3 retains C_prev), NT stores.
// ---------------------------------------------------------------------------
__global__ __launch_bounds__(kThreads)
void mlstm_stream(const float* __restrict__ C_prev,
                  const float* __restrict__ gq, const float* __restrict__ gk,
                  const float* __restrict__ gv, const float* __restrict__ go,
                  const float* __restrict__ gi, const float* __restrict__ gf,
                  const float* __restrict__ ginv,
                  float* __restrict__ out_C,
                  float* __restrict__ out_ht)
{
    const int pair = blockIdx.x >> 1;
    const int rblk = (blockIdx.x & 1) * kRB;    // row offset: 0 or 64
    const int tid  = threadIdx.x;
    const int r0   = tid >> 5;      // 0..7
    const int s    = tid & 31;      // col group (cols 4s..4s+3)

    __shared__ float sv_s[kRB];
    __shared__ float sh_s[kRB];

    if (tid < kRB / 4)
        reinterpret_cast<float4*>(sv_s)[tid] =
            reinterpret_cast<const float4*>(gv + (size_t)pair * kM + rblk)[tid];

    const float iv = gi[pair];
    const float fv = gf[pair];
    const float4 k4 = *reinterpret_cast<const float4*>(gk + (size_t)pair * kM + 4 * s);
    const float4 q4 = *reinterpret_cast<const float4*>(gq + (size_t)pair * kM + 4 * s);
    __syncthreads();

    const size_t cbase = (size_t)pair * (kM * kM) + (size_t)rblk * kM;
    const f32x4* cp = reinterpret_cast<const f32x4*>(C_prev + cbase);
    f32x4*       cn = reinterpret_cast<f32x4*>(out_C + cbase);

    // explicit load batch: 8 independent loads in flight
    f32x4 c4[8];
    #pragma unroll
    for (int j = 0; j < 8; ++j)
        c4[j] = cp[tid + kThreads * j];

    float hpart[8];
    #pragma unroll
    for (int j = 0; j < 8; ++j) {
        const int r = r0 + 8 * j;            // row within this 64-row slab
        const float ivr = iv * sv_s[r];
        f32x4 c_new;
        c_new.x = fv * c4[j].x + ivr * k4.x;
        c_new.y = fv * c4[j].y + ivr * k4.y;
        c_new.z = fv * c4[j].z + ivr * k4.z;
        c_new.w = fv * c4[j].w + ivr * k4.w;
        __builtin_nontemporal_store(c_new, &cn[tid + kThreads * j]);
        hpart[j] = c_new.x * q4.x + c_new.y * q4.y
                 + c_new.z * q4.z + c_new.w * q4.w;
    }

    #pragma unroll
    for (int j = 0; j < 8; ++j) {
        float v = hpart[j];
        v += __shfl_xor(v, 16, 64);
        v += __shfl_xor(v, 8, 64);
        v += __shfl_xor(v, 4, 64);
        v += __shfl_xor(v, 2, 64);
        v += __shfl_xor(v, 1, 64);
        if (s == 0) sh_s[r0 + 8 * j] = v;
    }
    __syncthreads();

    if (tid < kRB / 4) {
        const float inv = ginv[pair];
        const float4 h4 = reinterpret_cast<const float4*>(sh_s)[tid];
        const float4 o4 = reinterpret_cast<const float4*>(go + (size_t)pair * kM + rblk)[tid];
        float4 ht4;
        ht4.x = o4.x * h4.x * inv;
        ht4.y = o4.y * h4.y * inv;
        ht4.z = o4.z * h4.z * inv;
        ht4.w = o4.w * h4.w * inv;
        reinterpret_cast<float4*>(out_ht + (size_t)pair * kM + rblk)[tid] = ht4;
    }
}

extern "C" void kernel_launch(void* const* d_in, const int* in_sizes, int n_in,
                              void* d_out, int out_size, void* d_ws, size_t ws_size,
                              hipStream_t stream) {
    const float* x      = (const float*)d_in[0];
    const float* C_prev = (const float*)d_in[1];
    const float* n_prev = (const float*)d_in[2];
    const float* Wq = (const float*)d_in[3];
    const float* bq = (const float*)d_in[4];
    const float* Wk = (const float*)d_in[5];
    const float* bk = (const float*)d_in[6];
    const float* Wv = (const float*)d_in[7];
    const float* bv = (const float*)d_in[8];
    const float* wi = (const float*)d_in[9];
    const float* bi = (const float*)d_in[10];
    const float* wf = (const float*)d_in[11];
    const float* bf = (const float*)d_in[12];
    const float* Wo = (const float*)d_in[13];
    const float* bo = (const float*)d_in[14];

    float* out    = (float*)d_out;
    float* out_ht = out;                                    // (T,B,M)
    float* out_C  = out + (size_t)kNPairs * kM;             // (T,B,M,M)
    float* out_n  = out_C + (size_t)kNPairs * kM * kM;      // (T,B,M)

    // workspace layout (floats)
    float* ws = (float*)d_ws;
    const size_t gsz = (size_t)kNPairs * kM;                // 524288
    float* gq   = ws;
    float* gk   = gq + gsz;
    float* gv   = gk + gsz;
    float* go   = gv + gsz;
    float* gi   = go + gsz;
    float* gf   = gi + kNPairs;
    float* ginv = gf + kNPairs;

    mlstm_gates<<<dim3(kNPairs / kGP), dim3(kThreads), 0, stream>>>(
        x, n_prev, Wq, bq, Wk, bk, Wv, bv, wi, bi, wf, bf, Wo, bo,
        gq, gk, gv, go, gi, gf, ginv, out_n);

    mlstm_stream<<<dim3(kNPairs * (kM / kRB)), dim3(kThreads), 0, stream>>>(
        C_prev, gq, gk, gv, go, gi, gf, ginv, out_C, out_ht);
}